// Round 1
// baseline (700.535 us; speedup 1.0000x reference)
//
#include <hip/hip_runtime.h>
#include <math.h>

// Problem constants (fixed by the reference setup)
constexpr int B = 32;
constexpr int L = 4096;
constexpr int D = 1024;
constexpr float NEG_INF = -1e30f;

// One-pass online-softmax partials: CH waves per batch row, each wave owns
// L/CH consecutive sequence positions and all of D (16 floats per lane).
constexpr int CH  = 128;       // chunks (waves) per b
constexpr int RPW = L / CH;    // 32 rows per wave

// Workspace layout (floats):
//   scores : B*L            = 131072
//   pm     : B*CH           = 4096
//   pl     : B*CH           = 4096
//   Mden   : 2*B            = 64
//   pacc   : B*CH*D         = 4194304   (16 MB)
constexpr size_t WS_SCORES = 0;
constexpr size_t WS_PM     = WS_SCORES + (size_t)B * L;
constexpr size_t WS_PL     = WS_PM + (size_t)B * CH;
constexpr size_t WS_MDEN   = WS_PL + (size_t)B * CH;
constexpr size_t WS_PACC   = WS_MDEN + 2 * B;   // float4-aligned (divisible by 4)

__global__ __launch_bounds__(256) void pass1_kernel(
    const float* __restrict__ seq, const float* __restrict__ vec,
    const int* __restrict__ mask, float* __restrict__ scores,
    float* __restrict__ pm, float* __restrict__ pl, float* __restrict__ pacc)
{
    const int wave = blockIdx.x * 4 + (threadIdx.x >> 6);  // [0, B*CH)
    const int lane = threadIdx.x & 63;
    const int b = wave >> 7;          // wave / CH  (CH==128)
    const int c = wave & (CH - 1);
    const int l0 = c * RPW;

    // vector fragment: lane covers d = lane*4 + j*256, j=0..3
    const float4* v4 = (const float4*)(vec + (size_t)b * D);
    const float4 v0 = v4[lane], v1 = v4[lane + 64], v2 = v4[lane + 128], v3 = v4[lane + 192];

    float m = -INFINITY, lsum = 0.f;
    float4 a0 = {0,0,0,0}, a1 = {0,0,0,0}, a2 = {0,0,0,0}, a3 = {0,0,0,0};

    const float4* srow = (const float4*)(seq + ((size_t)b * L + l0) * D);
    const int rowbase = b * L + l0;

    for (int r = 0; r < RPW; ++r) {
        const float4* sp = srow + (size_t)r * (D / 4);
        const float4 s0 = sp[lane], s1 = sp[lane + 64], s2 = sp[lane + 128], s3 = sp[lane + 192];

        float part = s0.x*v0.x + s0.y*v0.y + s0.z*v0.z + s0.w*v0.w
                   + s1.x*v1.x + s1.y*v1.y + s1.z*v1.z + s1.w*v1.w
                   + s2.x*v2.x + s2.y*v2.y + s2.z*v2.z + s2.w*v2.w
                   + s3.x*v3.x + s3.y*v3.y + s3.z*v3.z + s3.w*v3.w;
        #pragma unroll
        for (int off = 32; off; off >>= 1)
            part += __shfl_xor(part, off, 64);

        const float sc = (mask[rowbase + r] > 0) ? part : NEG_INF;
        if (lane == 0) scores[rowbase + r] = sc;

        const float mn    = fmaxf(m, sc);
        const float scale = __expf(m - mn);     // exp(-inf)=0 on first row
        const float p     = __expf(sc - mn);
        lsum = lsum * scale + p;
        a0.x = a0.x*scale + p*s0.x;  a0.y = a0.y*scale + p*s0.y;
        a0.z = a0.z*scale + p*s0.z;  a0.w = a0.w*scale + p*s0.w;
        a1.x = a1.x*scale + p*s1.x;  a1.y = a1.y*scale + p*s1.y;
        a1.z = a1.z*scale + p*s1.z;  a1.w = a1.w*scale + p*s1.w;
        a2.x = a2.x*scale + p*s2.x;  a2.y = a2.y*scale + p*s2.y;
        a2.z = a2.z*scale + p*s2.z;  a2.w = a2.w*scale + p*s2.w;
        a3.x = a3.x*scale + p*s3.x;  a3.y = a3.y*scale + p*s3.y;
        a3.z = a3.z*scale + p*s3.z;  a3.w = a3.w*scale + p*s3.w;
        m = mn;
    }

    float4* aout = (float4*)(pacc + (size_t)wave * D);
    aout[lane] = a0; aout[lane + 64] = a1; aout[lane + 128] = a2; aout[lane + 192] = a3;
    if (lane == 0) { pm[wave] = m; pl[wave] = lsum; }
}

// grid (B, 8), 128 threads: block (b, y) reduces 128 chunk-partials over a
// 128-wide d-slice. M/denom recomputed per block (cheap, identical values).
__global__ __launch_bounds__(128) void combine_kernel(
    const float* __restrict__ pm, const float* __restrict__ pl,
    const float* __restrict__ pacc, float* __restrict__ pooled,
    float* __restrict__ Mden)
{
    const int b  = blockIdx.x;
    const int ds = blockIdx.y * 128;
    const int t  = threadIdx.x;        // 0..127

    __shared__ float red[128];
    __shared__ float wgt[128];

    const float mc = pm[b * CH + t];
    const float lc = pl[b * CH + t];

    red[t] = mc; __syncthreads();
    #pragma unroll
    for (int s = 64; s; s >>= 1) { if (t < s) red[t] = fmaxf(red[t], red[t + s]); __syncthreads(); }
    const float M = red[0];
    __syncthreads();

    const float e = __expf(mc - M);
    wgt[t] = e;
    red[t] = lc * e; __syncthreads();
    #pragma unroll
    for (int s = 64; s; s >>= 1) { if (t < s) red[t] += red[t + s]; __syncthreads(); }
    const float denom = red[0];
    const float inv = 1.f / denom;

    float acc = 0.f;
    const float* base = pacc + (size_t)b * CH * D + ds + t;
    #pragma unroll 4
    for (int c = 0; c < CH; ++c)
        acc += base[(size_t)c * D] * wgt[c];

    pooled[b * D + ds + t] = acc * inv;
    if (blockIdx.y == 0 && t == 0) { Mden[2*b] = M; Mden[2*b + 1] = denom; }
}

__global__ __launch_bounds__(256) void weights_kernel(
    const float* __restrict__ scores, const float* __restrict__ Mden,
    float* __restrict__ out_w)
{
    const int idx = blockIdx.x * 256 + threadIdx.x;   // < B*L
    const int b = idx >> 12;                          // / L (L==4096)
    const float M   = Mden[2*b];
    const float den = Mden[2*b + 1];
    out_w[idx] = __expf(scores[idx] - M) / den;
}

extern "C" void kernel_launch(void* const* d_in, const int* in_sizes, int n_in,
                              void* d_out, int out_size, void* d_ws, size_t ws_size,
                              hipStream_t stream) {
    const float* seq  = (const float*)d_in[0];
    const float* vec  = (const float*)d_in[1];
    const int*   mask = (const int*)d_in[2];
    float* out = (float*)d_out;           // pooled [B*D] then weights [B*L]

    float* ws     = (float*)d_ws;
    float* scores = ws + WS_SCORES;
    float* pm     = ws + WS_PM;
    float* pl     = ws + WS_PL;
    float* Mden   = ws + WS_MDEN;
    float* pacc   = ws + WS_PACC;

    pass1_kernel<<<(B * CH) / 4, 256, 0, stream>>>(seq, vec, mask, scores, pm, pl, pacc);
    combine_kernel<<<dim3(B, D / 128), 128, 0, stream>>>(pm, pl, pacc, out, Mden);
    weights_kernel<<<(B * L) / 256, 256, 0, stream>>>(scores, Mden, out + B * D);
}

// Round 2
// 692.335 us; speedup vs baseline: 1.0118x; 1.0118x over previous
//
#include <hip/hip_runtime.h>
#include <math.h>

// Problem constants (fixed by the reference setup)
constexpr int B = 32;
constexpr int L = 4096;
constexpr int D = 1024;
constexpr float NEG_INF = -1e30f;

// One-pass online-softmax partials: CH waves per batch row, each wave owns
// L/CH consecutive sequence positions and all of D (16 floats per lane).
constexpr int CH  = 128;       // chunks (waves) per b
constexpr int RPW = L / CH;    // 32 rows per wave

// Workspace layout (floats):
//   scores : B*L = 131072 | pm,pl : B*CH each | Mden : 2*B | pacc : B*CH*D (16 MB)
constexpr size_t WS_SCORES = 0;
constexpr size_t WS_PM     = WS_SCORES + (size_t)B * L;
constexpr size_t WS_PL     = WS_PM + (size_t)B * CH;
constexpr size_t WS_MDEN   = WS_PL + (size_t)B * CH;
constexpr size_t WS_PACC   = WS_MDEN + 2 * B;   // float4-aligned

__global__ __launch_bounds__(256, 4) void pass1_kernel(
    const float* __restrict__ seq, const float* __restrict__ vec,
    const int* __restrict__ mask, float* __restrict__ scores,
    float* __restrict__ pm, float* __restrict__ pl, float* __restrict__ pacc)
{
    const int wave = blockIdx.x * 4 + (threadIdx.x >> 6);  // [0, B*CH)
    const int lane = threadIdx.x & 63;
    const int b = wave >> 7;          // wave / CH  (CH==128)
    const int c = wave & (CH - 1);
    const int l0 = c * RPW;

    // vector fragment: lane covers d = lane*4 + j*256, j=0..3
    const float4* v4 = (const float4*)(vec + (size_t)b * D);
    const float4 v0 = v4[lane], v1 = v4[lane + 64], v2 = v4[lane + 128], v3 = v4[lane + 192];

    float m = -INFINITY, lsum = 0.f;
    float4 a0 = {0,0,0,0}, a1 = {0,0,0,0}, a2 = {0,0,0,0}, a3 = {0,0,0,0};

    const float4* srow = (const float4*)(seq + ((size_t)b * L + l0) * D);
    const int rowbase = b * L + l0;

    for (int it = 0; it < RPW / 4; ++it) {
        // uniform mask quad -> scalar load
        const int4 mk = *(const int4*)(mask + rowbase + it * 4);
        const int mks[4] = {mk.x, mk.y, mk.z, mk.w};

        // burst-load 4 rows (16 dwordx4 per lane) for ILP + VMEM occupancy
        float4 s[4][4];
        #pragma unroll
        for (int j = 0; j < 4; ++j) {
            const float4* sp = srow + (size_t)(it * 4 + j) * (D / 4);
            s[j][0] = sp[lane];       s[j][1] = sp[lane + 64];
            s[j][2] = sp[lane + 128]; s[j][3] = sp[lane + 192];
        }

        // 4 independent partial dots
        float dot[4];
        #pragma unroll
        for (int j = 0; j < 4; ++j) {
            dot[j] = s[j][0].x*v0.x + s[j][0].y*v0.y + s[j][0].z*v0.z + s[j][0].w*v0.w
                   + s[j][1].x*v1.x + s[j][1].y*v1.y + s[j][1].z*v1.z + s[j][1].w*v1.w
                   + s[j][2].x*v2.x + s[j][2].y*v2.y + s[j][2].z*v2.z + s[j][2].w*v2.w
                   + s[j][3].x*v3.x + s[j][3].y*v3.y + s[j][3].z*v3.z + s[j][3].w*v3.w;
        }
        // 4 interleaved butterfly chains (latency amortized 4x)
        #pragma unroll
        for (int off = 32; off; off >>= 1) {
            #pragma unroll
            for (int j = 0; j < 4; ++j) dot[j] += __shfl_xor(dot[j], off, 64);
        }

        float scv[4];
        #pragma unroll
        for (int j = 0; j < 4; ++j) {
            const float sc = (mks[j] > 0) ? dot[j] : NEG_INF;
            scv[j] = sc;
            // sc is wave-uniform -> uniform s_cbranch; rescale is rare (~4 of 32 rows)
            if (sc > m) {
                const float scale = __expf(m - sc);   // exp(-inf)=0 on first row
                lsum *= scale;
                a0.x*=scale; a0.y*=scale; a0.z*=scale; a0.w*=scale;
                a1.x*=scale; a1.y*=scale; a1.z*=scale; a1.w*=scale;
                a2.x*=scale; a2.y*=scale; a2.z*=scale; a2.w*=scale;
                a3.x*=scale; a3.y*=scale; a3.z*=scale; a3.w*=scale;
                m = sc;
            }
            const float p = __expf(sc - m);
            lsum += p;
            a0.x += p*s[j][0].x; a0.y += p*s[j][0].y; a0.z += p*s[j][0].z; a0.w += p*s[j][0].w;
            a1.x += p*s[j][1].x; a1.y += p*s[j][1].y; a1.z += p*s[j][1].z; a1.w += p*s[j][1].w;
            a2.x += p*s[j][2].x; a2.y += p*s[j][2].y; a2.z += p*s[j][2].z; a2.w += p*s[j][2].w;
            a3.x += p*s[j][3].x; a3.y += p*s[j][3].y; a3.z += p*s[j][3].z; a3.w += p*s[j][3].w;
        }
        // batched uniform score store (rowbase + it*4 is 16B-aligned)
        if (lane == 0) *(float4*)(scores + rowbase + it * 4) = make_float4(scv[0], scv[1], scv[2], scv[3]);
    }

    float4* aout = (float4*)(pacc + (size_t)wave * D);
    aout[lane] = a0; aout[lane + 64] = a1; aout[lane + 128] = a2; aout[lane + 192] = a3;
    if (lane == 0) { pm[wave] = m; pl[wave] = lsum; }
}

// grid (B, 8), 128 threads: block (b, y) reduces 128 chunk-partials over a
// 128-wide d-slice. M/denom recomputed per block (cheap, identical values).
__global__ __launch_bounds__(128) void combine_kernel(
    const float* __restrict__ pm, const float* __restrict__ pl,
    const float* __restrict__ pacc, float* __restrict__ pooled,
    float* __restrict__ Mden)
{
    const int b  = blockIdx.x;
    const int ds = blockIdx.y * 128;
    const int t  = threadIdx.x;        // 0..127

    __shared__ float red[128];
    __shared__ float wgt[128];

    const float mc = pm[b * CH + t];
    const float lc = pl[b * CH + t];

    red[t] = mc; __syncthreads();
    #pragma unroll
    for (int s = 64; s; s >>= 1) { if (t < s) red[t] = fmaxf(red[t], red[t + s]); __syncthreads(); }
    const float M = red[0];
    __syncthreads();

    const float e = __expf(mc - M);
    wgt[t] = e;
    red[t] = lc * e; __syncthreads();
    #pragma unroll
    for (int s = 64; s; s >>= 1) { if (t < s) red[t] += red[t + s]; __syncthreads(); }
    const float denom = red[0];
    const float inv = 1.f / denom;

    float acc = 0.f;
    const float* base = pacc + (size_t)b * CH * D + ds + t;
    #pragma unroll 8
    for (int c = 0; c < CH; ++c)
        acc += base[(size_t)c * D] * wgt[c];

    pooled[b * D + ds + t] = acc * inv;
    if (blockIdx.y == 0 && t == 0) { Mden[2*b] = M; Mden[2*b + 1] = denom; }
}

__global__ __launch_bounds__(256) void weights_kernel(
    const float* __restrict__ scores, const float* __restrict__ Mden,
    float* __restrict__ out_w)
{
    const int idx = blockIdx.x * 256 + threadIdx.x;   // < B*L
    const int b = idx >> 12;                          // / L (L==4096)
    const float M   = Mden[2*b];
    const float den = Mden[2*b + 1];
    out_w[idx] = __expf(scores[idx] - M) / den;
}

extern "C" void kernel_launch(void* const* d_in, const int* in_sizes, int n_in,
                              void* d_out, int out_size, void* d_ws, size_t ws_size,
                              hipStream_t stream) {
    const float* seq  = (const float*)d_in[0];
    const float* vec  = (const float*)d_in[1];
    const int*   mask = (const int*)d_in[2];
    float* out = (float*)d_out;           // pooled [B*D] then weights [B*L]

    float* ws     = (float*)d_ws;
    float* scores = ws + WS_SCORES;
    float* pm     = ws + WS_PM;
    float* pl     = ws + WS_PL;
    float* Mden   = ws + WS_MDEN;
    float* pacc   = ws + WS_PACC;

    pass1_kernel<<<(B * CH) / 4, 256, 0, stream>>>(seq, vec, mask, scores, pm, pl, pacc);
    combine_kernel<<<dim3(B, D / 128), 128, 0, stream>>>(pm, pl, pacc, out, Mden);
    weights_kernel<<<(B * L) / 256, 256, 0, stream>>>(scores, Mden, out + B * D);
}

// Round 3
// 668.076 us; speedup vs baseline: 1.0486x; 1.0363x over previous
//
#include <hip/hip_runtime.h>
#include <math.h>

// Problem constants (fixed by the reference setup)
constexpr int B = 32;
constexpr int L = 4096;
constexpr int D = 1024;
constexpr float NEG_INF = -1e30f;

// One-pass online-softmax partials: CH waves per batch row, each wave owns
// L/CH consecutive sequence positions and all of D (16 floats per lane).
constexpr int CH  = 128;       // chunks (waves) per b -> grid 1024 blocks = exactly 4/CU
constexpr int RPW = L / CH;    // 32 rows per wave

using f32x4 = __attribute__((ext_vector_type(4))) float;

// Workspace layout (floats):
//   scores : B*L = 131072 | pm,pl : B*CH each | Mden : 2*B | pacc : B*CH*D (16 MB)
constexpr size_t WS_SCORES = 0;
constexpr size_t WS_PM     = WS_SCORES + (size_t)B * L;
constexpr size_t WS_PL     = WS_PM + (size_t)B * CH;
constexpr size_t WS_MDEN   = WS_PL + (size_t)B * CH;
constexpr size_t WS_PACC   = WS_MDEN + 2 * B;   // 16B-aligned

// 2-row ILP: ~95 live VGPRs -> fits the 128-VGPR budget of 4 waves/SIMD with
// no spills (4-row staging in R2 blew past 128 and was neutral). Non-temporal
// seq loads: stream-once data, keep L2 for pacc.
__global__ __launch_bounds__(256, 4) void pass1_kernel(
    const float* __restrict__ seq, const float* __restrict__ vec,
    const int* __restrict__ mask, float* __restrict__ scores,
    float* __restrict__ pm, float* __restrict__ pl, float* __restrict__ pacc)
{
    const int wave = blockIdx.x * 4 + (threadIdx.x >> 6);  // [0, B*CH)
    const int lane = threadIdx.x & 63;
    const int b = wave >> 7;          // wave / CH  (CH==128)
    const int c = wave & (CH - 1);
    const int l0 = c * RPW;

    // vector fragment: lane covers d = lane*4 + j*256, j=0..3
    const f32x4* v4 = (const f32x4*)(vec + (size_t)b * D);
    const f32x4 v0 = v4[lane], v1 = v4[lane + 64], v2 = v4[lane + 128], v3 = v4[lane + 192];

    float m = -INFINITY, lsum = 0.f;
    f32x4 a0 = {0,0,0,0}, a1 = {0,0,0,0}, a2 = {0,0,0,0}, a3 = {0,0,0,0};

    const f32x4* srow = (const f32x4*)(seq + ((size_t)b * L + l0) * D);
    const int rowbase = b * L + l0;

    for (int it = 0; it < RPW / 2; ++it) {
        // uniform mask pair -> scalar load
        const int2 mk = *(const int2*)(mask + rowbase + it * 2);

        // burst-load 2 rows (8 dwordx4/lane, non-temporal) for MLP
        const f32x4* p0 = srow + (size_t)(it * 2) * (D / 4);
        const f32x4* p1 = p0 + (D / 4);
        f32x4 s00 = __builtin_nontemporal_load(p0 + lane);
        f32x4 s01 = __builtin_nontemporal_load(p0 + lane + 64);
        f32x4 s02 = __builtin_nontemporal_load(p0 + lane + 128);
        f32x4 s03 = __builtin_nontemporal_load(p0 + lane + 192);
        f32x4 s10 = __builtin_nontemporal_load(p1 + lane);
        f32x4 s11 = __builtin_nontemporal_load(p1 + lane + 64);
        f32x4 s12 = __builtin_nontemporal_load(p1 + lane + 128);
        f32x4 s13 = __builtin_nontemporal_load(p1 + lane + 192);

        // 2 independent partial dots
        f32x4 d0v = s00 * v0 + s01 * v1 + s02 * v2 + s03 * v3;
        f32x4 d1v = s10 * v0 + s11 * v1 + s12 * v2 + s13 * v3;
        float dot0 = d0v.x + d0v.y + d0v.z + d0v.w;
        float dot1 = d1v.x + d1v.y + d1v.z + d1v.w;

        // interleaved butterfly chains
        #pragma unroll
        for (int off = 32; off; off >>= 1) {
            dot0 += __shfl_xor(dot0, off, 64);
            dot1 += __shfl_xor(dot1, off, 64);
        }

        const float sc0 = (mk.x > 0) ? dot0 : NEG_INF;
        const float sc1 = (mk.y > 0) ? dot1 : NEG_INF;

        // row 0 — sc wave-uniform -> uniform branch; rescale rare (~5/32 rows)
        if (sc0 > m) {
            const float scale = __expf(m - sc0);   // exp(-inf)=0 on first row
            lsum *= scale;
            a0 *= scale; a1 *= scale; a2 *= scale; a3 *= scale;
            m = sc0;
        }
        {
            const float p = __expf(sc0 - m);
            lsum += p;
            a0 += p * s00; a1 += p * s01; a2 += p * s02; a3 += p * s03;
        }
        // row 1
        if (sc1 > m) {
            const float scale = __expf(m - sc1);
            lsum *= scale;
            a0 *= scale; a1 *= scale; a2 *= scale; a3 *= scale;
            m = sc1;
        }
        {
            const float p = __expf(sc1 - m);
            lsum += p;
            a0 += p * s10; a1 += p * s11; a2 += p * s12; a3 += p * s13;
        }

        if (lane == 0) *(float2*)(scores + rowbase + it * 2) = make_float2(sc0, sc1);
    }

    f32x4* aout = (f32x4*)(pacc + (size_t)wave * D);
    aout[lane] = a0; aout[lane + 64] = a1; aout[lane + 128] = a2; aout[lane + 192] = a3;
    if (lane == 0) { pm[wave] = m; pl[wave] = lsum; }
}

// grid (B, 8), 128 threads: block (b, y) reduces 128 chunk-partials over a
// 128-wide d-slice. M/denom recomputed per block (cheap, identical values).
__global__ __launch_bounds__(128) void combine_kernel(
    const float* __restrict__ pm, const float* __restrict__ pl,
    const float* __restrict__ pacc, float* __restrict__ pooled,
    float* __restrict__ Mden)
{
    const int b  = blockIdx.x;
    const int ds = blockIdx.y * 128;
    const int t  = threadIdx.x;        // 0..127

    __shared__ float red[128];
    __shared__ float wgt[128];

    const float mc = pm[b * CH + t];
    const float lc = pl[b * CH + t];

    red[t] = mc; __syncthreads();
    #pragma unroll
    for (int s = 64; s; s >>= 1) { if (t < s) red[t] = fmaxf(red[t], red[t + s]); __syncthreads(); }
    const float M = red[0];
    __syncthreads();

    const float e = __expf(mc - M);
    wgt[t] = e;
    red[t] = lc * e; __syncthreads();
    #pragma unroll
    for (int s = 64; s; s >>= 1) { if (t < s) red[t] += red[t + s]; __syncthreads(); }
    const float denom = red[0];
    const float inv = 1.f / denom;

    float acc = 0.f;
    const float* base = pacc + (size_t)b * CH * D + ds + t;
    #pragma unroll 8
    for (int c = 0; c < CH; ++c)
        acc += base[(size_t)c * D] * wgt[c];

    pooled[b * D + ds + t] = acc * inv;
    if (blockIdx.y == 0 && t == 0) { Mden[2*b] = M; Mden[2*b + 1] = denom; }
}

__global__ __launch_bounds__(256) void weights_kernel(
    const float* __restrict__ scores, const float* __restrict__ Mden,
    float* __restrict__ out_w)
{
    const int idx = blockIdx.x * 256 + threadIdx.x;   // < B*L
    const int b = idx >> 12;                          // / L (L==4096)
    const float M   = Mden[2*b];
    const float den = Mden[2*b + 1];
    out_w[idx] = __expf(scores[idx] - M) / den;
}

extern "C" void kernel_launch(void* const* d_in, const int* in_sizes, int n_in,
                              void* d_out, int out_size, void* d_ws, size_t ws_size,
                              hipStream_t stream) {
    const float* seq  = (const float*)d_in[0];
    const float* vec  = (const float*)d_in[1];
    const int*   mask = (const int*)d_in[2];
    float* out = (float*)d_out;           // pooled [B*D] then weights [B*L]

    float* ws     = (float*)d_ws;
    float* scores = ws + WS_SCORES;
    float* pm     = ws + WS_PM;
    float* pl     = ws + WS_PL;
    float* Mden   = ws + WS_MDEN;
    float* pacc   = ws + WS_PACC;

    pass1_kernel<<<(B * CH) / 4, 256, 0, stream>>>(seq, vec, mask, scores, pm, pl, pacc);
    combine_kernel<<<dim3(B, D / 128), 128, 0, stream>>>(pm, pl, pacc, out, Mden);
    weights_kernel<<<(B * L) / 256, 256, 0, stream>>>(scores, Mden, out + B * D);
}